// Round 1
// baseline (1404.526 us; speedup 1.0000x reference)
//
#include <hip/hip_runtime.h>
#include <cstdint>
#include <cstddef>

// Problem constants (fixed by the reference)
#define TDIM 2048   // tokens (B*S)
#define HDIM 2048   // hidden
#define IDIM 768    // intermediate
#define EXP  32     // experts
#define TOPK 4
#define TKTOT 8192  // TDIM*TOPK (every token selects exactly TOPK experts)
#define MAXMETA 96  // sum_e ceil(cnt_e/128) <= 8192/128 + 32 = 96

typedef __attribute__((ext_vector_type(8))) short short8;
typedef __attribute__((ext_vector_type(4))) float f32x4;

// ---------- workspace layout ----------
constexpr size_t OFF_XBF = 0;                                      // x as bf16 [T][H]
constexpr size_t OFF_ACT = OFF_XBF + (size_t)TDIM * HDIM * 2;      // act bf16 [TKTOT][I]
constexpr size_t OFF_LOG = OFF_ACT + (size_t)TKTOT * IDIM * 2;     // logits f32 [T][E]
constexpr size_t OFF_SEL = OFF_LOG + (size_t)TDIM * EXP * 4;       // sel int [T][4]
constexpr size_t OFF_WTS = OFF_SEL + (size_t)TDIM * TOPK * 4;      // weights f32 [T][4]
constexpr size_t OFF_STK = OFF_WTS + (size_t)TDIM * TOPK * 4;      // sorted token ids [TKTOT]
constexpr size_t OFF_SW  = OFF_STK + (size_t)TKTOT * 4;            // sorted weights [TKTOT]
constexpr size_t OFF_INV = OFF_SW  + (size_t)TKTOT * 4;            // inverse perm [T][4]
constexpr size_t OFF_CNT = OFF_INV + (size_t)TDIM * TOPK * 4;      // counts [E]
constexpr size_t OFF_CUR = OFF_CNT + EXP * 4;                      // cursors [E]
constexpr size_t OFF_OFS = OFF_CUR + EXP * 4;                      // offsets [E+1]
constexpr size_t OFF_MET = OFF_OFS + (EXP + 1) * 4;                // meta [96][2]
constexpr size_t OFF_NB  = OFF_MET + MAXMETA * 2 * 4;              // nblocks
constexpr size_t OFF_TMP = (OFF_NB + 4 + 255) & ~(size_t)255;      // tmp f32 [TKTOT][H] (optional)
constexpr size_t TMP_BYTES = (size_t)TKTOT * HDIM * 4;

// ---------- helpers ----------
__device__ __forceinline__ unsigned short f2bf(float f) {  // RNE f32->bf16
  unsigned u = __float_as_uint(f);
  u = (u + 0x7fffu + ((u >> 16) & 1u)) >> 16;
  return (unsigned short)u;
}
__device__ __forceinline__ unsigned pk2(float a, float b) {
  return (unsigned)f2bf(a) | ((unsigned)f2bf(b) << 16);
}
__device__ __forceinline__ void async16(void* lds, const void* g) {
  // global -> LDS direct copy, 16 B per lane; LDS dest = wave-uniform base + lane*16
  __builtin_amdgcn_global_load_lds((const __attribute__((address_space(1))) void*)g,
                                   (__attribute__((address_space(3))) void*)lds, 16, 0, 0);
}

// ---------- x f32 -> bf16 ----------
__global__ __launch_bounds__(256) void k_cvt(const float* __restrict__ x,
                                             unsigned short* __restrict__ xb) {
  int i = blockIdx.x * 256 + threadIdx.x;          // 8 elems per thread
  const float4* s = (const float4*)x;
  float4 a = s[2 * i], b = s[2 * i + 1];
  uint4 o;
  o.x = pk2(a.x, a.y); o.y = pk2(a.z, a.w);
  o.z = pk2(b.x, b.y); o.w = pk2(b.z, b.w);
  ((uint4*)xb)[i] = o;
}

// ---------- router logits: [T,H] x [E,H]^T -> [T,E], f32 ----------
__global__ __launch_bounds__(256) void k_router(const float* __restrict__ x,
                                                const float* __restrict__ gw,
                                                float* __restrict__ logits) {
  __shared__ float smx[4 * HDIM];                  // 32 KB: 4 tokens
  int tid = threadIdx.x;
  int t0 = blockIdx.x * 4;
  const float4* src = (const float4*)(x + (size_t)t0 * HDIM);
  float4* dst = (float4*)smx;
#pragma unroll
  for (int i = 0; i < 8; i++) dst[i * 256 + tid] = src[i * 256 + tid];
  __syncthreads();

  int e = tid >> 3, sl = tid & 7;                  // 32 experts x 8 k-slices
  float acc[4] = {0.f, 0.f, 0.f, 0.f};
  const float* gptr = gw + (size_t)e * HDIM + sl * 256;
#pragma unroll 4
  for (int j = 0; j < 64; j++) {
    float4 g4 = *(const float4*)(gptr + j * 4);
#pragma unroll
    for (int tt = 0; tt < 4; tt++) {
      float4 xa = *(const float4*)&smx[tt * HDIM + sl * 256 + j * 4];
      acc[tt] += g4.x * xa.x + g4.y * xa.y + g4.z * xa.z + g4.w * xa.w;
    }
  }
  __syncthreads();
#pragma unroll
  for (int tt = 0; tt < 4; tt++) smx[(tt * EXP + e) * 8 + sl] = acc[tt];
  __syncthreads();
  if (tid < 128) {
    int tt = tid >> 5, ee = tid & 31;
    float s = 0.f;
#pragma unroll
    for (int q = 0; q < 8; q++) s += smx[(tt * EXP + ee) * 8 + q];
    logits[(size_t)(t0 + tt) * EXP + ee] = s;
  }
}

// ---------- softmax + top-4 + renorm ----------
__global__ __launch_bounds__(256) void k_topk(const float* __restrict__ logits,
                                              int* __restrict__ sel,
                                              float* __restrict__ wts,
                                              int* __restrict__ cnt) {
  int t = blockIdx.x * 256 + threadIdx.x;
  float p[EXP];
  float mx = -1e30f;
#pragma unroll
  for (int e = 0; e < EXP; e++) { p[e] = logits[(size_t)t * EXP + e]; mx = fmaxf(mx, p[e]); }
#pragma unroll
  for (int e = 0; e < EXP; e++) p[e] = __expf(p[e] - mx);
  // top-4 by prob (== by logit); renorm cancels the softmax denominator exactly.
  unsigned used = 0; int si[TOPK]; float sv[TOPK]; float tot = 0.f;
  for (int k = 0; k < TOPK; k++) {
    float bm = -1.f; int bi = 0;
#pragma unroll
    for (int e = 0; e < EXP; e++) {
      bool ok = !((used >> e) & 1) && (p[e] > bm);
      bm = ok ? p[e] : bm;
      bi = ok ? e : bi;
    }
    used |= 1u << bi; si[k] = bi; sv[k] = bm; tot += bm;
  }
  float inv = 1.f / tot;
#pragma unroll
  for (int k = 0; k < TOPK; k++) {
    sel[t * TOPK + k] = si[k];
    wts[t * TOPK + k] = sv[k] * inv;
    atomicAdd(&cnt[si[k]], 1);
  }
}

// ---------- serial scan: offsets, cursors, block schedule ----------
__global__ void k_scan(const int* __restrict__ cnt, int* __restrict__ offs,
                       int* __restrict__ cur, int* __restrict__ meta,
                       int* __restrict__ nb) {
  if (threadIdx.x == 0 && blockIdx.x == 0) {
    int off = 0, n = 0;
    for (int e = 0; e < EXP; e++) {
      offs[e] = off; cur[e] = off;
      int c = cnt[e];
      for (int r = 0; r < c && n < MAXMETA; r += 128) { meta[n * 2] = e; meta[n * 2 + 1] = r; n++; }
      off += c;
    }
    offs[EXP] = off;
    nb[0] = n;
  }
}

// ---------- scatter tokens into expert-sorted order ----------
__global__ __launch_bounds__(256) void k_scatter(const int* __restrict__ sel,
                                                 const float* __restrict__ wts,
                                                 int* __restrict__ cur,
                                                 int* __restrict__ stok,
                                                 float* __restrict__ sw,
                                                 int* __restrict__ inv) {
  int t = blockIdx.x * 256 + threadIdx.x;
#pragma unroll
  for (int k = 0; k < TOPK; k++) {
    int e = sel[t * TOPK + k];
    int p = atomicAdd(&cur[e], 1);
    stok[p] = t;
    sw[p] = wts[t * TOPK + k];
    inv[t * TOPK + k] = p;
  }
}

// ---------- GEMM1: act[p][i] = silu(x@Wg) * (x@Wu) * w,  bf16 out ----------
__global__ __launch_bounds__(256, 2) void k_gemm1(
    const float* __restrict__ Wg, const float* __restrict__ Wu,
    const unsigned short* __restrict__ xb,
    const int* __restrict__ stok, const float* __restrict__ sw,
    const int* __restrict__ cnt, const int* __restrict__ offs,
    const int* __restrict__ meta, const int* __restrict__ nb,
    unsigned short* __restrict__ act) {
  int bid = blockIdx.x;
  if (bid >= nb[0]) return;
  int e = meta[bid * 2 + 0];
  int r0 = meta[bid * 2 + 1];
  int pos0 = offs[e] + r0;
  int rows = min(128, cnt[e] - r0);
  int n0 = blockIdx.y * 128;

  __shared__ unsigned short smA[128 * 64];   // [m][k-chunk swizzled], 16 KB
  __shared__ unsigned short smBg[128 * 64];  // [n][k-chunk swizzled]
  __shared__ unsigned short smBu[128 * 64];
  __shared__ int smTok[128];
  __shared__ float smW[128];

  int tid = threadIdx.x;
  if (tid < 128) {
    int r = tid;
    int rr = (r < rows) ? r : 0;
    smTok[r] = stok[pos0 + rr];
    smW[r] = (r < rows) ? sw[pos0 + r] : 0.f;
  }
  __syncthreads();

  int lane = tid & 63, w = tid >> 6;
  int waveM = w >> 1, waveN = w & 1;

  // A staging: global_load_lds, 4 passes of 32 rows; chunk XOR-swizzle by row&7
  const unsigned short* aP[4];
  unsigned short* aD[4];
#pragma unroll
  for (int p = 0; p < 4; p++) {
    int r = p * 32 + w * 8 + (lane >> 3);
    aP[p] = xb + (size_t)smTok[r] * HDIM + (((lane & 7) ^ (r & 7)) << 3);
    aD[p] = &smA[(p * 32 + w * 8) * 64];
  }
  // B staging: thread = one n-column, half the k-tile; scalar k-major loads (coalesced across lanes)
  int bn = tid & 127, kh = tid >> 7;
  const float* pG = Wg + (size_t)e * HDIM * IDIM + (size_t)(kh * 32) * IDIM + n0 + bn;
  const float* pU = Wu + (size_t)e * HDIM * IDIM + (size_t)(kh * 32) * IDIM + n0 + bn;

  f32x4 accG[4][4], accU[4][4];
#pragma unroll
  for (int a = 0; a < 4; a++)
#pragma unroll
    for (int b = 0; b < 4; b++) { accG[a][b] = {0.f, 0.f, 0.f, 0.f}; accU[a][b] = {0.f, 0.f, 0.f, 0.f}; }

  int lm = lane & 15, lq = lane >> 4;

  for (int kt = 0; kt < HDIM / 64; kt++) {
    __syncthreads();
#pragma unroll
    for (int p = 0; p < 4; p++) async16(aD[p], aP[p]);
    {
      const float* q = pG; float v[32];
#pragma unroll
      for (int j = 0; j < 32; j++) { v[j] = *q; q += IDIM; }
#pragma unroll
      for (int jj = 0; jj < 4; jj++) {
        short8 o;
#pragma unroll
        for (int z = 0; z < 8; z++) o[z] = (short)f2bf(v[jj * 8 + z]);
        int ck = kh * 4 + jj;
        *(short8*)&smBg[bn * 64 + ((ck ^ (bn & 7)) << 3)] = o;
      }
    }
    {
      const float* q = pU; float v[32];
#pragma unroll
      for (int j = 0; j < 32; j++) { v[j] = *q; q += IDIM; }
#pragma unroll
      for (int jj = 0; jj < 4; jj++) {
        short8 o;
#pragma unroll
        for (int z = 0; z < 8; z++) o[z] = (short)f2bf(v[jj * 8 + z]);
        int ck = kh * 4 + jj;
        *(short8*)&smBu[bn * 64 + ((ck ^ (bn & 7)) << 3)] = o;
      }
    }
    __syncthreads();
#pragma unroll
    for (int s = 0; s < 2; s++) {
      int kq = s * 4 + lq;
      short8 af[4], bg[4], bu[4];
#pragma unroll
      for (int mt = 0; mt < 4; mt++) {
        int m = waveM * 64 + mt * 16 + lm;
        af[mt] = *(const short8*)&smA[m * 64 + ((kq ^ (m & 7)) << 3)];
      }
#pragma unroll
      for (int nt = 0; nt < 4; nt++) {
        int n = waveN * 64 + nt * 16 + lm;
        int off = n * 64 + ((kq ^ (n & 7)) << 3);
        bg[nt] = *(const short8*)&smBg[off];
        bu[nt] = *(const short8*)&smBu[off];
      }
#pragma unroll
      for (int mt = 0; mt < 4; mt++)
#pragma unroll
        for (int nt = 0; nt < 4; nt++) {
          accG[mt][nt] = __builtin_amdgcn_mfma_f32_16x16x32_bf16(af[mt], bg[nt], accG[mt][nt], 0, 0, 0);
          accU[mt][nt] = __builtin_amdgcn_mfma_f32_16x16x32_bf16(af[mt], bu[nt], accU[mt][nt], 0, 0, 0);
        }
    }
#pragma unroll
    for (int p = 0; p < 4; p++) aP[p] += 64;
    pG += (size_t)64 * IDIM;
    pU += (size_t)64 * IDIM;
  }

  // epilogue: silu(g)*u*w -> bf16 act (C/D layout: col=lane&15, row=(lane>>4)*4+i)
#pragma unroll
  for (int mt = 0; mt < 4; mt++)
#pragma unroll
    for (int nt = 0; nt < 4; nt++) {
      int n = n0 + waveN * 64 + nt * 16 + lm;
#pragma unroll
      for (int i = 0; i < 4; i++) {
        int r = waveM * 64 + mt * 16 + lq * 4 + i;
        if (r < rows) {
          float g = accG[mt][nt][i], u = accU[mt][nt][i];
          float sg = g / (1.f + __expf(-g));
          act[(size_t)(pos0 + r) * IDIM + n] = f2bf(sg * u * smW[r]);
        }
      }
    }
}

// ---------- GEMM2: down-proj; mode 0 = store tmp[pos][h], mode 1 = atomic into out[token][h] ----------
__global__ __launch_bounds__(256, 2) void k_gemm2(
    const float* __restrict__ Wd, const unsigned short* __restrict__ act,
    const int* __restrict__ stok, const int* __restrict__ cnt,
    const int* __restrict__ offs, const int* __restrict__ meta,
    const int* __restrict__ nb, float* __restrict__ dst, int mode) {
  int bid = blockIdx.x;
  if (bid >= nb[0]) return;
  int e = meta[bid * 2 + 0];
  int r0 = meta[bid * 2 + 1];
  int pos0 = offs[e] + r0;
  int rows = min(128, cnt[e] - r0);
  int n0 = blockIdx.y * 128;

  __shared__ unsigned short smA[128 * 64];
  __shared__ unsigned short smB[128 * 64];
  __shared__ int smTok[128];

  int tid = threadIdx.x;
  if (tid < 128) {
    int r = tid;
    int rr = (r < rows) ? r : 0;
    smTok[r] = stok[pos0 + rr];
  }
  __syncthreads();

  int lane = tid & 63, w = tid >> 6;
  int waveM = w >> 1, waveN = w & 1;

  const unsigned short* aP[4];
  unsigned short* aD[4];
#pragma unroll
  for (int p = 0; p < 4; p++) {
    int r = p * 32 + w * 8 + (lane >> 3);
    int pp = pos0 + r; if (pp > TKTOT - 1) pp = TKTOT - 1;  // clamp (guarded at store)
    aP[p] = act + (size_t)pp * IDIM + (((lane & 7) ^ (r & 7)) << 3);
    aD[p] = &smA[(p * 32 + w * 8) * 64];
  }
  int bn = tid & 127, kh = tid >> 7;
  const float* pD = Wd + (size_t)e * IDIM * HDIM + (size_t)(kh * 32) * HDIM + n0 + bn;

  f32x4 acc[4][4];
#pragma unroll
  for (int a = 0; a < 4; a++)
#pragma unroll
    for (int b = 0; b < 4; b++) acc[a][b] = {0.f, 0.f, 0.f, 0.f};

  int lm = lane & 15, lq = lane >> 4;

  for (int kt = 0; kt < IDIM / 64; kt++) {
    __syncthreads();
#pragma unroll
    for (int p = 0; p < 4; p++) async16(aD[p], aP[p]);
    {
      const float* q = pD; float v[32];
#pragma unroll
      for (int j = 0; j < 32; j++) { v[j] = *q; q += HDIM; }
#pragma unroll
      for (int jj = 0; jj < 4; jj++) {
        short8 o;
#pragma unroll
        for (int z = 0; z < 8; z++) o[z] = (short)f2bf(v[jj * 8 + z]);
        int ck = kh * 4 + jj;
        *(short8*)&smB[bn * 64 + ((ck ^ (bn & 7)) << 3)] = o;
      }
    }
    __syncthreads();
#pragma unroll
    for (int s = 0; s < 2; s++) {
      int kq = s * 4 + lq;
      short8 af[4], bf[4];
#pragma unroll
      for (int mt = 0; mt < 4; mt++) {
        int m = waveM * 64 + mt * 16 + lm;
        af[mt] = *(const short8*)&smA[m * 64 + ((kq ^ (m & 7)) << 3)];
      }
#pragma unroll
      for (int nt = 0; nt < 4; nt++) {
        int n = waveN * 64 + nt * 16 + lm;
        bf[nt] = *(const short8*)&smB[n * 64 + ((kq ^ (n & 7)) << 3)];
      }
#pragma unroll
      for (int mt = 0; mt < 4; mt++)
#pragma unroll
        for (int nt = 0; nt < 4; nt++)
          acc[mt][nt] = __builtin_amdgcn_mfma_f32_16x16x32_bf16(af[mt], bf[nt], acc[mt][nt], 0, 0, 0);
    }
#pragma unroll
    for (int p = 0; p < 4; p++) aP[p] += 64;
    pD += (size_t)64 * HDIM;
  }

#pragma unroll
  for (int mt = 0; mt < 4; mt++)
#pragma unroll
    for (int nt = 0; nt < 4; nt++) {
      int n = n0 + waveN * 64 + nt * 16 + lm;
#pragma unroll
      for (int i = 0; i < 4; i++) {
        int r = waveM * 64 + mt * 16 + lq * 4 + i;
        if (r < rows) {
          float val = acc[mt][nt][i];
          if (mode == 0) {
            dst[(size_t)(pos0 + r) * HDIM + n] = val;
          } else {
            __hip_atomic_fetch_add(&dst[(size_t)smTok[r] * HDIM + n], val,
                                   __ATOMIC_RELAXED, __HIP_MEMORY_SCOPE_AGENT);
          }
        }
      }
    }
}

// ---------- gather-reduce 4 contributions per token ----------
__global__ __launch_bounds__(256) void k_reduce(const float* __restrict__ tmp,
                                                const int* __restrict__ inv,
                                                float* __restrict__ out) {
  int u = blockIdx.x * 256 + threadIdx.x;  // TDIM * 512 threads, float4 each
  int t = u >> 9, c = u & 511;
  int i0 = inv[t * 4 + 0], i1 = inv[t * 4 + 1], i2 = inv[t * 4 + 2], i3 = inv[t * 4 + 3];
  float4 a = *(const float4*)(tmp + (size_t)i0 * HDIM + c * 4);
  float4 b = *(const float4*)(tmp + (size_t)i1 * HDIM + c * 4);
  float4 d = *(const float4*)(tmp + (size_t)i2 * HDIM + c * 4);
  float4 e = *(const float4*)(tmp + (size_t)i3 * HDIM + c * 4);
  float4 s;
  s.x = a.x + b.x + d.x + e.x;
  s.y = a.y + b.y + d.y + e.y;
  s.z = a.z + b.z + d.z + e.z;
  s.w = a.w + b.w + d.w + e.w;
  *(float4*)(out + (size_t)t * HDIM + c * 4) = s;
}

extern "C" void kernel_launch(void* const* d_in, const int* in_sizes, int n_in,
                              void* d_out, int out_size, void* d_ws, size_t ws_size,
                              hipStream_t stream) {
  const float* x  = (const float*)d_in[0];
  const float* gw = (const float*)d_in[1];
  const float* Wg = (const float*)d_in[2];
  const float* Wu = (const float*)d_in[3];
  const float* Wd = (const float*)d_in[4];
  float* out = (float*)d_out;

  char* ws = (char*)d_ws;
  unsigned short* xb  = (unsigned short*)(ws + OFF_XBF);
  unsigned short* act = (unsigned short*)(ws + OFF_ACT);
  float* logits = (float*)(ws + OFF_LOG);
  int*   sel    = (int*)(ws + OFF_SEL);
  float* wts    = (float*)(ws + OFF_WTS);
  int*   stok   = (int*)(ws + OFF_STK);
  float* sw     = (float*)(ws + OFF_SW);
  int*   inv    = (int*)(ws + OFF_INV);
  int*   cnt    = (int*)(ws + OFF_CNT);
  int*   cur    = (int*)(ws + OFF_CUR);
  int*   offs   = (int*)(ws + OFF_OFS);
  int*   meta   = (int*)(ws + OFF_MET);
  int*   nb     = (int*)(ws + OFF_NB);
  float* tmp    = (float*)(ws + OFF_TMP);

  bool useTmp = ws_size >= OFF_TMP + TMP_BYTES;

  hipMemsetAsync(cnt, 0, EXP * 4, stream);
  k_cvt<<<(TDIM * HDIM / 8) / 256, 256, 0, stream>>>(x, xb);
  k_router<<<TDIM / 4, 256, 0, stream>>>(x, gw, logits);
  k_topk<<<TDIM / 256, 256, 0, stream>>>(logits, sel, wts, cnt);
  k_scan<<<1, 64, 0, stream>>>(cnt, offs, cur, meta, nb);
  k_scatter<<<TDIM / 256, 256, 0, stream>>>(sel, wts, cur, stok, sw, inv);
  k_gemm1<<<dim3(MAXMETA, IDIM / 128), 256, 0, stream>>>(Wg, Wu, xb, stok, sw, cnt, offs, meta, nb, act);
  if (useTmp) {
    k_gemm2<<<dim3(MAXMETA, HDIM / 128), 256, 0, stream>>>(Wd, act, stok, cnt, offs, meta, nb, tmp, 0);
    k_reduce<<<(TDIM * 512) / 256, 256, 0, stream>>>(tmp, inv, out);
  } else {
    hipMemsetAsync(out, 0, (size_t)TDIM * HDIM * 4, stream);
    k_gemm2<<<dim3(MAXMETA, HDIM / 128), 256, 0, stream>>>(Wd, act, stok, cnt, offs, meta, nb, out, 1);
  }
}

// Round 2
// 827.860 us; speedup vs baseline: 1.6966x; 1.6966x over previous
//
#include <hip/hip_runtime.h>
#include <cstdint>
#include <cstddef>

// Problem constants (fixed by the reference)
#define TDIM 2048   // tokens (B*S)
#define HDIM 2048   // hidden
#define IDIM 768    // intermediate
#define EXP  32     // experts
#define TOPK 4
#define TKTOT 8192  // TDIM*TOPK
#define MAXMETA 96  // sum_e ceil(cnt_e/128) <= 8192/128 + 32 = 96

typedef __attribute__((ext_vector_type(8))) short short8;
typedef __attribute__((ext_vector_type(4))) float f32x4;

// ---------- workspace layout (prefix identical to round 1 for safe fallback) ----------
constexpr size_t OFF_XBF = 0;                                      // x bf16 [T][H]
constexpr size_t OFF_ACT = OFF_XBF + (size_t)TDIM * HDIM * 2;      // act bf16 [TKTOT][I]
constexpr size_t OFF_LOG = OFF_ACT + (size_t)TKTOT * IDIM * 2;     // logits f32 [T][E]
constexpr size_t OFF_SEL = OFF_LOG + (size_t)TDIM * EXP * 4;
constexpr size_t OFF_WTS = OFF_SEL + (size_t)TDIM * TOPK * 4;
constexpr size_t OFF_STK = OFF_WTS + (size_t)TDIM * TOPK * 4;
constexpr size_t OFF_SW  = OFF_STK + (size_t)TKTOT * 4;
constexpr size_t OFF_INV = OFF_SW  + (size_t)TKTOT * 4;
constexpr size_t OFF_CNT = OFF_INV + (size_t)TDIM * TOPK * 4;
constexpr size_t OFF_CUR = OFF_CNT + EXP * 4;
constexpr size_t OFF_OFS = OFF_CUR + EXP * 4;
constexpr size_t OFF_MET = OFF_OFS + (EXP + 1) * 4;
constexpr size_t OFF_NB  = OFF_MET + MAXMETA * 2 * 4;
constexpr size_t OFF_TMP = (OFF_NB + 4 + 255) & ~(size_t)255;      // tmp f32 [TKTOT][H]
constexpr size_t TMP_BYTES = (size_t)TKTOT * HDIM * 4;
// bf16 transposed weights (new)
constexpr size_t WB_BYTES = (size_t)EXP * HDIM * IDIM * 2;         // 100.66 MB each
constexpr size_t OFF_WGB = (OFF_TMP + TMP_BYTES + 255) & ~(size_t)255;
constexpr size_t OFF_WUB = OFF_WGB + WB_BYTES;
constexpr size_t OFF_WDB = OFF_WUB + WB_BYTES;
constexpr size_t NEED_BF = OFF_WDB + WB_BYTES;

// ---------- helpers ----------
__device__ __forceinline__ unsigned short f2bf(float f) {  // RNE f32->bf16
  unsigned u = __float_as_uint(f);
  u = (u + 0x7fffu + ((u >> 16) & 1u)) >> 16;
  return (unsigned short)u;
}
__device__ __forceinline__ unsigned pk2(float a, float b) {
  return (unsigned)f2bf(a) | ((unsigned)f2bf(b) << 16);
}
__device__ __forceinline__ void async16(void* lds, const void* g) {
  __builtin_amdgcn_global_load_lds((const __attribute__((address_space(1))) void*)g,
                                   (__attribute__((address_space(3))) void*)lds, 16, 0, 0);
}

// ---------- x f32 -> bf16 ----------
__global__ __launch_bounds__(256) void k_cvt(const float* __restrict__ x,
                                             unsigned short* __restrict__ xb) {
  int i = blockIdx.x * 256 + threadIdx.x;
  const float4* s = (const float4*)x;
  float4 a = s[2 * i], b = s[2 * i + 1];
  uint4 o;
  o.x = pk2(a.x, a.y); o.y = pk2(a.z, a.w);
  o.z = pk2(b.x, b.y); o.w = pk2(b.z, b.w);
  ((uint4*)xb)[i] = o;
}

// ---------- weight convert+transpose: src f32 [z][R][C] -> dst bf16 [z][C][R] ----------
__global__ __launch_bounds__(256) void k_trw(const float* __restrict__ src,
                                             unsigned short* __restrict__ dst,
                                             int R, int C) {
  __shared__ float sm[64 * 65];
  int t = threadIdx.x;
  int c0 = blockIdx.x * 64, r0 = blockIdx.y * 64;
  size_t base = (size_t)blockIdx.z * R * C;
  const float* s = src + base + (size_t)r0 * C + c0;
#pragma unroll
  for (int p = 0; p < 4; p++) {
    int rl = p * 16 + (t >> 4), cl = (t & 15) * 4;
    float4 v = *(const float4*)(s + (size_t)rl * C + cl);
    float* d = &sm[rl * 65 + cl];
    d[0] = v.x; d[1] = v.y; d[2] = v.z; d[3] = v.w;
  }
  __syncthreads();
  unsigned short* o = dst + base + (size_t)c0 * R + r0;
#pragma unroll
  for (int q = 0; q < 4; q++) {
    int cl = q * 16 + (t >> 4), rq = (t & 15) * 4;
    float v0 = sm[(rq + 0) * 65 + cl], v1 = sm[(rq + 1) * 65 + cl];
    float v2 = sm[(rq + 2) * 65 + cl], v3 = sm[(rq + 3) * 65 + cl];
    uint2 u; u.x = pk2(v0, v1); u.y = pk2(v2, v3);
    *(uint2*)(o + (size_t)cl * R + rq) = u;
  }
}

// ---------- router logits ----------
__global__ __launch_bounds__(256) void k_router(const float* __restrict__ x,
                                                const float* __restrict__ gw,
                                                float* __restrict__ logits) {
  __shared__ float smx[4 * HDIM];
  int tid = threadIdx.x;
  int t0 = blockIdx.x * 4;
  const float4* src = (const float4*)(x + (size_t)t0 * HDIM);
  float4* dst = (float4*)smx;
#pragma unroll
  for (int i = 0; i < 8; i++) dst[i * 256 + tid] = src[i * 256 + tid];
  __syncthreads();
  int e = tid >> 3, sl = tid & 7;
  float acc[4] = {0.f, 0.f, 0.f, 0.f};
  const float* gptr = gw + (size_t)e * HDIM + sl * 256;
#pragma unroll 4
  for (int j = 0; j < 64; j++) {
    float4 g4 = *(const float4*)(gptr + j * 4);
#pragma unroll
    for (int tt = 0; tt < 4; tt++) {
      float4 xa = *(const float4*)&smx[tt * HDIM + sl * 256 + j * 4];
      acc[tt] += g4.x * xa.x + g4.y * xa.y + g4.z * xa.z + g4.w * xa.w;
    }
  }
  __syncthreads();
#pragma unroll
  for (int tt = 0; tt < 4; tt++) smx[(tt * EXP + e) * 8 + sl] = acc[tt];
  __syncthreads();
  if (tid < 128) {
    int tt = tid >> 5, ee = tid & 31;
    float s = 0.f;
#pragma unroll
    for (int q = 0; q < 8; q++) s += smx[(tt * EXP + ee) * 8 + q];
    logits[(size_t)(t0 + tt) * EXP + ee] = s;
  }
}

// ---------- softmax + top-4 + renorm ----------
__global__ __launch_bounds__(256) void k_topk(const float* __restrict__ logits,
                                              int* __restrict__ sel,
                                              float* __restrict__ wts,
                                              int* __restrict__ cnt) {
  int t = blockIdx.x * 256 + threadIdx.x;
  float p[EXP];
  float mx = -1e30f;
#pragma unroll
  for (int e = 0; e < EXP; e++) { p[e] = logits[(size_t)t * EXP + e]; mx = fmaxf(mx, p[e]); }
#pragma unroll
  for (int e = 0; e < EXP; e++) p[e] = __expf(p[e] - mx);
  unsigned used = 0; int si[TOPK]; float sv[TOPK]; float tot = 0.f;
  for (int k = 0; k < TOPK; k++) {
    float bm = -1.f; int bi = 0;
#pragma unroll
    for (int e = 0; e < EXP; e++) {
      bool ok = !((used >> e) & 1) && (p[e] > bm);
      bm = ok ? p[e] : bm;
      bi = ok ? e : bi;
    }
    used |= 1u << bi; si[k] = bi; sv[k] = bm; tot += bm;
  }
  float inv = 1.f / tot;
#pragma unroll
  for (int k = 0; k < TOPK; k++) {
    sel[t * TOPK + k] = si[k];
    wts[t * TOPK + k] = sv[k] * inv;
    atomicAdd(&cnt[si[k]], 1);
  }
}

// ---------- serial scan ----------
__global__ void k_scan(const int* __restrict__ cnt, int* __restrict__ offs,
                       int* __restrict__ cur, int* __restrict__ meta,
                       int* __restrict__ nb) {
  if (threadIdx.x == 0 && blockIdx.x == 0) {
    int off = 0, n = 0;
    for (int e = 0; e < EXP; e++) {
      offs[e] = off; cur[e] = off;
      int c = cnt[e];
      for (int r = 0; r < c && n < MAXMETA; r += 128) { meta[n * 2] = e; meta[n * 2 + 1] = r; n++; }
      off += c;
    }
    offs[EXP] = off;
    nb[0] = n;
  }
}

// ---------- scatter ----------
__global__ __launch_bounds__(256) void k_scatter(const int* __restrict__ sel,
                                                 const float* __restrict__ wts,
                                                 int* __restrict__ cur,
                                                 int* __restrict__ stok,
                                                 float* __restrict__ sw,
                                                 int* __restrict__ inv) {
  int t = blockIdx.x * 256 + threadIdx.x;
#pragma unroll
  for (int k = 0; k < TOPK; k++) {
    int e = sel[t * TOPK + k];
    int p = atomicAdd(&cur[e], 1);
    stok[p] = t;
    sw[p] = wts[t * TOPK + k];
    inv[t * TOPK + k] = p;
  }
}

// ---------- NEW GEMM1 (bf16 weights, all-async staging): M=128 N=64 BK=64 ----------
__global__ __launch_bounds__(256, 3) void k_gemm1b(
    const unsigned short* __restrict__ Wgb, const unsigned short* __restrict__ Wub,
    const unsigned short* __restrict__ xb,
    const int* __restrict__ stok, const float* __restrict__ sw,
    const int* __restrict__ cnt, const int* __restrict__ offs,
    const int* __restrict__ meta, const int* __restrict__ nb,
    unsigned short* __restrict__ act) {
  int bid = blockIdx.x;
  if (bid >= nb[0]) return;
  int e = meta[bid * 2], r0 = meta[bid * 2 + 1];
  int pos0 = offs[e] + r0;
  int rows = min(128, cnt[e] - r0);
  int n0 = blockIdx.y * 64;

  __shared__ unsigned short smA[128 * 64];   // 16 KB
  __shared__ unsigned short smBg[64 * 64];   // 8 KB
  __shared__ unsigned short smBu[64 * 64];   // 8 KB
  __shared__ int smTok[128];
  __shared__ float smW[128];

  int tid = threadIdx.x;
  if (tid < 128) {
    int rr = (tid < rows) ? tid : 0;
    smTok[tid] = stok[pos0 + rr];
    smW[tid] = (tid < rows) ? sw[pos0 + tid] : 0.f;
  }
  __syncthreads();

  int lane = tid & 63, w = tid >> 6;
  int waveM = w >> 1, waveN = w & 1;

  const unsigned short* aP[4];
  unsigned short* aD[4];
#pragma unroll
  for (int p = 0; p < 4; p++) {
    int r = p * 32 + w * 8 + (lane >> 3);
    aP[p] = xb + (size_t)smTok[r] * HDIM + (((lane & 7) ^ (r & 7)) << 3);
    aD[p] = &smA[(p * 32 + w * 8) * 64];
  }
  const unsigned short* gP[2]; unsigned short* gD[2];
  const unsigned short* uP[2]; unsigned short* uD[2];
  size_t wbase = (size_t)e * IDIM * HDIM;
#pragma unroll
  for (int p = 0; p < 2; p++) {
    int nr = p * 32 + w * 8 + (lane >> 3);
    size_t go = wbase + (size_t)(n0 + nr) * HDIM + (((lane & 7) ^ (nr & 7)) << 3);
    gP[p] = Wgb + go; uP[p] = Wub + go;
    gD[p] = &smBg[(p * 32 + w * 8) * 64];
    uD[p] = &smBu[(p * 32 + w * 8) * 64];
  }

  f32x4 accG[4][2], accU[4][2];
#pragma unroll
  for (int a = 0; a < 4; a++)
#pragma unroll
    for (int b = 0; b < 2; b++) { accG[a][b] = {0.f,0.f,0.f,0.f}; accU[a][b] = {0.f,0.f,0.f,0.f}; }

  int lm = lane & 15, lq = lane >> 4;

  for (int kt = 0; kt < HDIM / 64; kt++) {
    __syncthreads();
#pragma unroll
    for (int p = 0; p < 4; p++) async16(aD[p], aP[p]);
#pragma unroll
    for (int p = 0; p < 2; p++) async16(gD[p], gP[p]);
#pragma unroll
    for (int p = 0; p < 2; p++) async16(uD[p], uP[p]);
    __syncthreads();
#pragma unroll
    for (int s = 0; s < 2; s++) {
      int kq = s * 4 + lq;
      short8 af[4], bg[2], bu[2];
#pragma unroll
      for (int mt = 0; mt < 4; mt++) {
        int m = waveM * 64 + mt * 16 + lm;
        af[mt] = *(const short8*)&smA[m * 64 + ((kq ^ (m & 7)) << 3)];
      }
#pragma unroll
      for (int nt = 0; nt < 2; nt++) {
        int n = waveN * 32 + nt * 16 + lm;
        int off = n * 64 + ((kq ^ (n & 7)) << 3);
        bg[nt] = *(const short8*)&smBg[off];
        bu[nt] = *(const short8*)&smBu[off];
      }
#pragma unroll
      for (int mt = 0; mt < 4; mt++)
#pragma unroll
        for (int nt = 0; nt < 2; nt++) {
          accG[mt][nt] = __builtin_amdgcn_mfma_f32_16x16x32_bf16(af[mt], bg[nt], accG[mt][nt], 0, 0, 0);
          accU[mt][nt] = __builtin_amdgcn_mfma_f32_16x16x32_bf16(af[mt], bu[nt], accU[mt][nt], 0, 0, 0);
        }
    }
#pragma unroll
    for (int p = 0; p < 4; p++) aP[p] += 64;
#pragma unroll
    for (int p = 0; p < 2; p++) { gP[p] += 64; uP[p] += 64; }
  }

#pragma unroll
  for (int mt = 0; mt < 4; mt++)
#pragma unroll
    for (int nt = 0; nt < 2; nt++) {
      int n = n0 + waveN * 32 + nt * 16 + lm;
#pragma unroll
      for (int i = 0; i < 4; i++) {
        int r = waveM * 64 + mt * 16 + lq * 4 + i;
        if (r < rows) {
          float g = accG[mt][nt][i], u = accU[mt][nt][i];
          float sg = g / (1.f + __expf(-g));
          act[(size_t)(pos0 + r) * IDIM + n] = f2bf(sg * u * smW[r]);
        }
      }
    }
}

// ---------- NEW GEMM2 (bf16 Wd', all-async staging): M=128 N=128 BK=64 ----------
__global__ __launch_bounds__(256, 3) void k_gemm2b(
    const unsigned short* __restrict__ Wdb, const unsigned short* __restrict__ act,
    const int* __restrict__ cnt, const int* __restrict__ offs,
    const int* __restrict__ meta, const int* __restrict__ nb,
    float* __restrict__ tmp) {
  int bid = blockIdx.x;
  if (bid >= nb[0]) return;
  int e = meta[bid * 2], r0 = meta[bid * 2 + 1];
  int pos0 = offs[e] + r0;
  int rows = min(128, cnt[e] - r0);
  int n0 = blockIdx.y * 128;

  __shared__ unsigned short smA[128 * 64];
  __shared__ unsigned short smB[128 * 64];

  int tid = threadIdx.x;
  int lane = tid & 63, w = tid >> 6;
  int waveM = w >> 1, waveN = w & 1;

  const unsigned short* aP[4];
  unsigned short* aD[4];
#pragma unroll
  for (int p = 0; p < 4; p++) {
    int r = p * 32 + w * 8 + (lane >> 3);
    int pp = pos0 + r; if (pp > TKTOT - 1) pp = TKTOT - 1;
    aP[p] = act + (size_t)pp * IDIM + (((lane & 7) ^ (r & 7)) << 3);
    aD[p] = &smA[(p * 32 + w * 8) * 64];
  }
  const unsigned short* bP[4]; unsigned short* bD[4];
  size_t wbase = (size_t)e * IDIM * HDIM;  // Wdb is [E][H][I]
#pragma unroll
  for (int p = 0; p < 4; p++) {
    int nr = p * 32 + w * 8 + (lane >> 3);
    bP[p] = Wdb + wbase + (size_t)(n0 + nr) * IDIM + (((lane & 7) ^ (nr & 7)) << 3);
    bD[p] = &smB[(p * 32 + w * 8) * 64];
  }

  f32x4 acc[4][4];
#pragma unroll
  for (int a = 0; a < 4; a++)
#pragma unroll
    for (int b = 0; b < 4; b++) acc[a][b] = {0.f, 0.f, 0.f, 0.f};

  int lm = lane & 15, lq = lane >> 4;

  for (int kt = 0; kt < IDIM / 64; kt++) {
    __syncthreads();
#pragma unroll
    for (int p = 0; p < 4; p++) async16(aD[p], aP[p]);
#pragma unroll
    for (int p = 0; p < 4; p++) async16(bD[p], bP[p]);
    __syncthreads();
#pragma unroll
    for (int s = 0; s < 2; s++) {
      int kq = s * 4 + lq;
      short8 af[4], bf[4];
#pragma unroll
      for (int mt = 0; mt < 4; mt++) {
        int m = waveM * 64 + mt * 16 + lm;
        af[mt] = *(const short8*)&smA[m * 64 + ((kq ^ (m & 7)) << 3)];
      }
#pragma unroll
      for (int nt = 0; nt < 4; nt++) {
        int n = waveN * 64 + nt * 16 + lm;
        bf[nt] = *(const short8*)&smB[n * 64 + ((kq ^ (n & 7)) << 3)];
      }
#pragma unroll
      for (int mt = 0; mt < 4; mt++)
#pragma unroll
        for (int nt = 0; nt < 4; nt++)
          acc[mt][nt] = __builtin_amdgcn_mfma_f32_16x16x32_bf16(af[mt], bf[nt], acc[mt][nt], 0, 0, 0);
    }
#pragma unroll
    for (int p = 0; p < 4; p++) { aP[p] += 64; bP[p] += 64; }
  }

#pragma unroll
  for (int mt = 0; mt < 4; mt++)
#pragma unroll
    for (int nt = 0; nt < 4; nt++) {
      int n = n0 + waveN * 64 + nt * 16 + lm;
#pragma unroll
      for (int i = 0; i < 4; i++) {
        int r = waveM * 64 + mt * 16 + lq * 4 + i;
        if (r < rows) tmp[(size_t)(pos0 + r) * HDIM + n] = acc[mt][nt][i];
      }
    }
}

// ---------- FALLBACK GEMM1 (round-1, f32 weights) ----------
__global__ __launch_bounds__(256, 2) void k_gemm1(
    const float* __restrict__ Wg, const float* __restrict__ Wu,
    const unsigned short* __restrict__ xb,
    const int* __restrict__ stok, const float* __restrict__ sw,
    const int* __restrict__ cnt, const int* __restrict__ offs,
    const int* __restrict__ meta, const int* __restrict__ nb,
    unsigned short* __restrict__ act) {
  int bid = blockIdx.x;
  if (bid >= nb[0]) return;
  int e = meta[bid * 2 + 0];
  int r0 = meta[bid * 2 + 1];
  int pos0 = offs[e] + r0;
  int rows = min(128, cnt[e] - r0);
  int n0 = blockIdx.y * 128;

  __shared__ unsigned short smA[128 * 64];
  __shared__ unsigned short smBg[128 * 64];
  __shared__ unsigned short smBu[128 * 64];
  __shared__ int smTok[128];
  __shared__ float smW[128];

  int tid = threadIdx.x;
  if (tid < 128) {
    int r = tid;
    int rr = (r < rows) ? r : 0;
    smTok[r] = stok[pos0 + rr];
    smW[r] = (r < rows) ? sw[pos0 + r] : 0.f;
  }
  __syncthreads();

  int lane = tid & 63, w = tid >> 6;
  int waveM = w >> 1, waveN = w & 1;

  const unsigned short* aP[4];
  unsigned short* aD[4];
#pragma unroll
  for (int p = 0; p < 4; p++) {
    int r = p * 32 + w * 8 + (lane >> 3);
    aP[p] = xb + (size_t)smTok[r] * HDIM + (((lane & 7) ^ (r & 7)) << 3);
    aD[p] = &smA[(p * 32 + w * 8) * 64];
  }
  int bn = tid & 127, kh = tid >> 7;
  const float* pG = Wg + (size_t)e * HDIM * IDIM + (size_t)(kh * 32) * IDIM + n0 + bn;
  const float* pU = Wu + (size_t)e * HDIM * IDIM + (size_t)(kh * 32) * IDIM + n0 + bn;

  f32x4 accG[4][4], accU[4][4];
#pragma unroll
  for (int a = 0; a < 4; a++)
#pragma unroll
    for (int b = 0; b < 4; b++) { accG[a][b] = {0.f,0.f,0.f,0.f}; accU[a][b] = {0.f,0.f,0.f,0.f}; }

  int lm = lane & 15, lq = lane >> 4;

  for (int kt = 0; kt < HDIM / 64; kt++) {
    __syncthreads();
#pragma unroll
    for (int p = 0; p < 4; p++) async16(aD[p], aP[p]);
    {
      const float* q = pG; float v[32];
#pragma unroll
      for (int j = 0; j < 32; j++) { v[j] = *q; q += IDIM; }
#pragma unroll
      for (int jj = 0; jj < 4; jj++) {
        short8 o;
#pragma unroll
        for (int z = 0; z < 8; z++) o[z] = (short)f2bf(v[jj * 8 + z]);
        int ck = kh * 4 + jj;
        *(short8*)&smBg[bn * 64 + ((ck ^ (bn & 7)) << 3)] = o;
      }
    }
    {
      const float* q = pU; float v[32];
#pragma unroll
      for (int j = 0; j < 32; j++) { v[j] = *q; q += IDIM; }
#pragma unroll
      for (int jj = 0; jj < 4; jj++) {
        short8 o;
#pragma unroll
        for (int z = 0; z < 8; z++) o[z] = (short)f2bf(v[jj * 8 + z]);
        int ck = kh * 4 + jj;
        *(short8*)&smBu[bn * 64 + ((ck ^ (bn & 7)) << 3)] = o;
      }
    }
    __syncthreads();
#pragma unroll
    for (int s = 0; s < 2; s++) {
      int kq = s * 4 + lq;
      short8 af[4], bg[4], bu[4];
#pragma unroll
      for (int mt = 0; mt < 4; mt++) {
        int m = waveM * 64 + mt * 16 + lm;
        af[mt] = *(const short8*)&smA[m * 64 + ((kq ^ (m & 7)) << 3)];
      }
#pragma unroll
      for (int nt = 0; nt < 4; nt++) {
        int n = waveN * 64 + nt * 16 + lm;
        int off = n * 64 + ((kq ^ (n & 7)) << 3);
        bg[nt] = *(const short8*)&smBg[off];
        bu[nt] = *(const short8*)&smBu[off];
      }
#pragma unroll
      for (int mt = 0; mt < 4; mt++)
#pragma unroll
        for (int nt = 0; nt < 4; nt++) {
          accG[mt][nt] = __builtin_amdgcn_mfma_f32_16x16x32_bf16(af[mt], bg[nt], accG[mt][nt], 0, 0, 0);
          accU[mt][nt] = __builtin_amdgcn_mfma_f32_16x16x32_bf16(af[mt], bu[nt], accU[mt][nt], 0, 0, 0);
        }
    }
#pragma unroll
    for (int p = 0; p < 4; p++) aP[p] += 64;
    pG += (size_t)64 * IDIM;
    pU += (size_t)64 * IDIM;
  }

#pragma unroll
  for (int mt = 0; mt < 4; mt++)
#pragma unroll
    for (int nt = 0; nt < 4; nt++) {
      int n = n0 + waveN * 64 + nt * 16 + lm;
#pragma unroll
      for (int i = 0; i < 4; i++) {
        int r = waveM * 64 + mt * 16 + lq * 4 + i;
        if (r < rows) {
          float g = accG[mt][nt][i], u = accU[mt][nt][i];
          float sg = g / (1.f + __expf(-g));
          act[(size_t)(pos0 + r) * IDIM + n] = f2bf(sg * u * smW[r]);
        }
      }
    }
}

// ---------- FALLBACK GEMM2 (round-1, f32 Wd) ----------
__global__ __launch_bounds__(256, 2) void k_gemm2(
    const float* __restrict__ Wd, const unsigned short* __restrict__ act,
    const int* __restrict__ stok, const int* __restrict__ cnt,
    const int* __restrict__ offs, const int* __restrict__ meta,
    const int* __restrict__ nb, float* __restrict__ dst, int mode) {
  int bid = blockIdx.x;
  if (bid >= nb[0]) return;
  int e = meta[bid * 2 + 0];
  int r0 = meta[bid * 2 + 1];
  int pos0 = offs[e] + r0;
  int rows = min(128, cnt[e] - r0);
  int n0 = blockIdx.y * 128;

  __shared__ unsigned short smA[128 * 64];
  __shared__ unsigned short smB[128 * 64];
  __shared__ int smTok[128];

  int tid = threadIdx.x;
  if (tid < 128) {
    int r = tid;
    int rr = (r < rows) ? r : 0;
    smTok[r] = stok[pos0 + rr];
  }
  __syncthreads();

  int lane = tid & 63, w = tid >> 6;
  int waveM = w >> 1, waveN = w & 1;

  const unsigned short* aP[4];
  unsigned short* aD[4];
#pragma unroll
  for (int p = 0; p < 4; p++) {
    int r = p * 32 + w * 8 + (lane >> 3);
    int pp = pos0 + r; if (pp > TKTOT - 1) pp = TKTOT - 1;
    aP[p] = act + (size_t)pp * IDIM + (((lane & 7) ^ (r & 7)) << 3);
    aD[p] = &smA[(p * 32 + w * 8) * 64];
  }
  int bn = tid & 127, kh = tid >> 7;
  const float* pD = Wd + (size_t)e * IDIM * HDIM + (size_t)(kh * 32) * HDIM + n0 + bn;

  f32x4 acc[4][4];
#pragma unroll
  for (int a = 0; a < 4; a++)
#pragma unroll
    for (int b = 0; b < 4; b++) acc[a][b] = {0.f, 0.f, 0.f, 0.f};

  int lm = lane & 15, lq = lane >> 4;

  for (int kt = 0; kt < IDIM / 64; kt++) {
    __syncthreads();
#pragma unroll
    for (int p = 0; p < 4; p++) async16(aD[p], aP[p]);
    {
      const float* q = pD; float v[32];
#pragma unroll
      for (int j = 0; j < 32; j++) { v[j] = *q; q += HDIM; }
#pragma unroll
      for (int jj = 0; jj < 4; jj++) {
        short8 o;
#pragma unroll
        for (int z = 0; z < 8; z++) o[z] = (short)f2bf(v[jj * 8 + z]);
        int ck = kh * 4 + jj;
        *(short8*)&smB[bn * 64 + ((ck ^ (bn & 7)) << 3)] = o;
      }
    }
    __syncthreads();
#pragma unroll
    for (int s = 0; s < 2; s++) {
      int kq = s * 4 + lq;
      short8 af[4], bf[4];
#pragma unroll
      for (int mt = 0; mt < 4; mt++) {
        int m = waveM * 64 + mt * 16 + lm;
        af[mt] = *(const short8*)&smA[m * 64 + ((kq ^ (m & 7)) << 3)];
      }
#pragma unroll
      for (int nt = 0; nt < 4; nt++) {
        int n = waveN * 64 + nt * 16 + lm;
        bf[nt] = *(const short8*)&smB[n * 64 + ((kq ^ (n & 7)) << 3)];
      }
#pragma unroll
      for (int mt = 0; mt < 4; mt++)
#pragma unroll
        for (int nt = 0; nt < 4; nt++)
          acc[mt][nt] = __builtin_amdgcn_mfma_f32_16x16x32_bf16(af[mt], bf[nt], acc[mt][nt], 0, 0, 0);
    }
#pragma unroll
    for (int p = 0; p < 4; p++) aP[p] += 64;
    pD += (size_t)64 * HDIM;
  }

#pragma unroll
  for (int mt = 0; mt < 4; mt++)
#pragma unroll
    for (int nt = 0; nt < 4; nt++) {
      int n = n0 + waveN * 64 + nt * 16 + lm;
#pragma unroll
      for (int i = 0; i < 4; i++) {
        int r = waveM * 64 + mt * 16 + lq * 4 + i;
        if (r < rows) {
          float val = acc[mt][nt][i];
          if (mode == 0) {
            dst[(size_t)(pos0 + r) * HDIM + n] = val;
          } else {
            __hip_atomic_fetch_add(&dst[(size_t)smTok[r] * HDIM + n], val,
                                   __ATOMIC_RELAXED, __HIP_MEMORY_SCOPE_AGENT);
          }
        }
      }
    }
}

// ---------- gather-reduce ----------
__global__ __launch_bounds__(256) void k_reduce(const float* __restrict__ tmp,
                                                const int* __restrict__ inv,
                                                float* __restrict__ out) {
  int u = blockIdx.x * 256 + threadIdx.x;
  int t = u >> 9, c = u & 511;
  int i0 = inv[t * 4 + 0], i1 = inv[t * 4 + 1], i2 = inv[t * 4 + 2], i3 = inv[t * 4 + 3];
  float4 a = *(const float4*)(tmp + (size_t)i0 * HDIM + c * 4);
  float4 b = *(const float4*)(tmp + (size_t)i1 * HDIM + c * 4);
  float4 d = *(const float4*)(tmp + (size_t)i2 * HDIM + c * 4);
  float4 e = *(const float4*)(tmp + (size_t)i3 * HDIM + c * 4);
  float4 s;
  s.x = a.x + b.x + d.x + e.x;
  s.y = a.y + b.y + d.y + e.y;
  s.z = a.z + b.z + d.z + e.z;
  s.w = a.w + b.w + d.w + e.w;
  *(float4*)(out + (size_t)t * HDIM + c * 4) = s;
}

extern "C" void kernel_launch(void* const* d_in, const int* in_sizes, int n_in,
                              void* d_out, int out_size, void* d_ws, size_t ws_size,
                              hipStream_t stream) {
  const float* x  = (const float*)d_in[0];
  const float* gw = (const float*)d_in[1];
  const float* Wg = (const float*)d_in[2];
  const float* Wu = (const float*)d_in[3];
  const float* Wd = (const float*)d_in[4];
  float* out = (float*)d_out;

  char* ws = (char*)d_ws;
  unsigned short* xb  = (unsigned short*)(ws + OFF_XBF);
  unsigned short* act = (unsigned short*)(ws + OFF_ACT);
  float* logits = (float*)(ws + OFF_LOG);
  int*   sel    = (int*)(ws + OFF_SEL);
  float* wts    = (float*)(ws + OFF_WTS);
  int*   stok   = (int*)(ws + OFF_STK);
  float* sw     = (float*)(ws + OFF_SW);
  int*   inv    = (int*)(ws + OFF_INV);
  int*   cnt    = (int*)(ws + OFF_CNT);
  int*   cur    = (int*)(ws + OFF_CUR);
  int*   offs   = (int*)(ws + OFF_OFS);
  int*   meta   = (int*)(ws + OFF_MET);
  int*   nb     = (int*)(ws + OFF_NB);
  float* tmp    = (float*)(ws + OFF_TMP);
  unsigned short* Wgb = (unsigned short*)(ws + OFF_WGB);
  unsigned short* Wub = (unsigned short*)(ws + OFF_WUB);
  unsigned short* Wdb = (unsigned short*)(ws + OFF_WDB);

  bool useTmp = ws_size >= OFF_TMP + TMP_BYTES;
  bool useBF  = ws_size >= NEED_BF;   // bf16-transposed-weight fast path

  hipMemsetAsync(cnt, 0, EXP * 4, stream);
  k_cvt<<<(TDIM * HDIM / 8) / 256, 256, 0, stream>>>(x, xb);
  k_router<<<TDIM / 4, 256, 0, stream>>>(x, gw, logits);
  k_topk<<<TDIM / 256, 256, 0, stream>>>(logits, sel, wts, cnt);
  k_scan<<<1, 64, 0, stream>>>(cnt, offs, cur, meta, nb);
  k_scatter<<<TDIM / 256, 256, 0, stream>>>(sel, wts, cur, stok, sw, inv);

  if (useBF) {
    // convert+transpose weights to bf16 n-major
    k_trw<<<dim3(IDIM / 64, HDIM / 64, EXP), 256, 0, stream>>>(Wg, Wgb, HDIM, IDIM);
    k_trw<<<dim3(IDIM / 64, HDIM / 64, EXP), 256, 0, stream>>>(Wu, Wub, HDIM, IDIM);
    k_trw<<<dim3(HDIM / 64, IDIM / 64, EXP), 256, 0, stream>>>(Wd, Wdb, IDIM, HDIM);
    k_gemm1b<<<dim3(MAXMETA, IDIM / 64), 256, 0, stream>>>(Wgb, Wub, xb, stok, sw, cnt, offs, meta, nb, act);
    k_gemm2b<<<dim3(MAXMETA, HDIM / 128), 256, 0, stream>>>(Wdb, act, cnt, offs, meta, nb, tmp);
    k_reduce<<<(TDIM * 512) / 256, 256, 0, stream>>>(tmp, inv, out);
  } else {
    k_gemm1<<<dim3(MAXMETA, IDIM / 128), 256, 0, stream>>>(Wg, Wu, xb, stok, sw, cnt, offs, meta, nb, act);
    if (useTmp) {
      k_gemm2<<<dim3(MAXMETA, HDIM / 128), 256, 0, stream>>>(Wd, act, stok, cnt, offs, meta, nb, tmp, 0);
      k_reduce<<<(TDIM * 512) / 256, 256, 0, stream>>>(tmp, inv, out);
    } else {
      hipMemsetAsync(out, 0, (size_t)TDIM * HDIM * 4, stream);
      k_gemm2<<<dim3(MAXMETA, HDIM / 128), 256, 0, stream>>>(Wd, act, stok, cnt, offs, meta, nb, out, 1);
    }
  }
}